// Round 1
// baseline (1534.221 us; speedup 1.0000x reference)
//
#include <hip/hip_runtime.h>
#include <hip/hip_bf16.h>

#define D 128
#define LN_EPS 1e-5f

// ---------------------------------------------------------------------------
// Kernel 1: transpose W [D,D] -> WT [D,D], WT[k][t] = W[t][k]
// Tiny (16K elements), one-shot.
// ---------------------------------------------------------------------------
__global__ void transpose_w(const float* __restrict__ W, float* __restrict__ WT) {
    int i = blockIdx.x * blockDim.x + threadIdx.x;
    if (i >= D * D) return;
    int r = i >> 7;        // row of W (output feature)
    int c = i & (D - 1);   // col of W (input feature)
    WT[c * D + r] = W[r * D + c];
}

// ---------------------------------------------------------------------------
// Kernel 2: scatter SpMM.  32 threads per edge; each thread handles one
// float4 chunk (4 dims) of the 128-dim row.  float4 gather from x[col],
// 4x atomicAdd into support[row].
// ---------------------------------------------------------------------------
__global__ void spmm_scatter(const float* __restrict__ x,
                             const float* __restrict__ edge_val,
                             const int* __restrict__ edge_row,
                             const int* __restrict__ edge_col,
                             float* __restrict__ support,
                             int E) {
    int gid = blockIdx.x * blockDim.x + threadIdx.x;
    int e = gid >> 5;          // 32 threads per edge
    if (e >= E) return;
    int q = gid & 31;          // float4 chunk index 0..31

    int col = edge_col[e];
    int row = edge_row[e];
    float val = edge_val[e];

    const float4* xv = (const float4*)(x + (size_t)col * D);
    float4 v = xv[q];

    float* sp = support + (size_t)row * D + q * 4;
    atomicAdd(sp + 0, val * v.x);
    atomicAdd(sp + 1, val * v.y);
    atomicAdd(sp + 2, val * v.z);
    atomicAdd(sp + 3, val * v.w);
}

// ---------------------------------------------------------------------------
// Kernel 3: fused linear (h = support @ W^T + b) + LayerNorm + ReLU.
// One 128-thread block per row.  support row staged in LDS (broadcast
// reads), WT read coalesced across lanes (hot in L1/L2).
// ---------------------------------------------------------------------------
__global__ void __launch_bounds__(D) linear_ln_relu(
    const float* __restrict__ support,
    const float* __restrict__ WT,      // WT[k][t] = W[t][k]
    const float* __restrict__ b,
    const float* __restrict__ gamma,
    const float* __restrict__ beta,
    float* __restrict__ out,
    int N) {
    int row = blockIdx.x;
    if (row >= N) return;
    int t = threadIdx.x;

    __shared__ float s[D];
    __shared__ float psum[2], psq[2];

    s[t] = support[(size_t)row * D + t];
    __syncthreads();

    // h[t] = b[t] + sum_k s[k] * WT[k*D + t]
    float acc = 0.f;
#pragma unroll 8
    for (int k = 0; k < D; ++k) {
        acc = fmaf(s[k], WT[k * D + t], acc);
    }
    float h = acc + b[t];

    // --- LayerNorm reduction across the 128 outputs (2 waves) ---
    float sum = h, sq = h * h;
#pragma unroll
    for (int off = 32; off > 0; off >>= 1) {
        sum += __shfl_down(sum, off, 64);
        sq  += __shfl_down(sq, off, 64);
    }
    int wave = t >> 6;
    if ((t & 63) == 0) { psum[wave] = sum; psq[wave] = sq; }
    __syncthreads();
    float tot   = psum[0] + psum[1];
    float totsq = psq[0] + psq[1];

    float mu  = tot * (1.0f / D);
    float var = totsq * (1.0f / D) - mu * mu;
    float inv = rsqrtf(var + LN_EPS);

    float y = (h - mu) * inv * gamma[t] + beta[t];
    out[(size_t)row * D + t] = fmaxf(y, 0.f);
}

// ---------------------------------------------------------------------------
// Launch
// ---------------------------------------------------------------------------
extern "C" void kernel_launch(void* const* d_in, const int* in_sizes, int n_in,
                              void* d_out, int out_size, void* d_ws, size_t ws_size,
                              hipStream_t stream) {
    const float* x        = (const float*)d_in[0];
    const float* edge_val = (const float*)d_in[1];
    const float* W        = (const float*)d_in[2];
    const float* b        = (const float*)d_in[3];
    const float* gamma    = (const float*)d_in[4];
    const float* beta     = (const float*)d_in[5];
    const int*   edge_row = (const int*)d_in[6];
    const int*   edge_col = (const int*)d_in[7];

    const int N = in_sizes[0] / D;
    const int E = in_sizes[1];

    float* support = (float*)d_ws;                       // N*D floats
    float* WT      = (float*)d_ws + (size_t)N * D;       // D*D floats

    // zero the accumulation buffer (ws is poisoned before every call)
    hipMemsetAsync(support, 0, (size_t)N * D * sizeof(float), stream);

    // transpose W
    {
        int threads = 256;
        int blocks = (D * D + threads - 1) / threads;
        transpose_w<<<blocks, threads, 0, stream>>>(W, WT);
    }

    // scatter SpMM
    {
        long long total = (long long)E * 32;
        int threads = 256;
        int blocks = (int)((total + threads - 1) / threads);
        spmm_scatter<<<blocks, threads, 0, stream>>>(x, edge_val, edge_row,
                                                     edge_col, support, E);
    }

    // fused linear + LN + ReLU
    {
        linear_ln_relu<<<N, D, 0, stream>>>(support, WT, b, gamma, beta,
                                            (float*)d_out, N);
    }
}

// Round 2
// 357.558 us; speedup vs baseline: 4.2908x; 4.2908x over previous
//
#include <hip/hip_runtime.h>
#include <hip/hip_bf16.h>

#define D 128
#define LN_EPS 1e-5f
#define TM 8          // rows per block in linear kernel

// ---------------------------------------------------------------------------
// transpose W [D,D] -> WT [D,D], WT[k][t] = W[t][k]
// ---------------------------------------------------------------------------
__global__ void transpose_w(const float* __restrict__ W, float* __restrict__ WT) {
    int i = blockIdx.x * blockDim.x + threadIdx.x;
    if (i >= D * D) return;
    int r = i >> 7;
    int c = i & (D - 1);
    WT[c * D + r] = W[r * D + c];
}

// ---------------------------------------------------------------------------
// counting sort of edges by row: histogram -> exclusive scan -> scatter
// ---------------------------------------------------------------------------
__global__ void hist_kernel(const int* __restrict__ edge_row,
                            int* __restrict__ counts, int E) {
    int e = blockIdx.x * blockDim.x + threadIdx.x;
    if (e < E) atomicAdd(&counts[edge_row[e]], 1);
}

__global__ void scan1(const int* __restrict__ counts, int* __restrict__ excl,
                      int* __restrict__ bsums, int n) {
    __shared__ int tmp[2][256];
    int t = threadIdx.x;
    int i = blockIdx.x * 256 + t;
    int v = (i < n) ? counts[i] : 0;
    tmp[0][t] = v;
    __syncthreads();
    int buf = 0;
    for (int off = 1; off < 256; off <<= 1) {
        int x = tmp[buf][t];
        if (t >= off) x += tmp[buf][t - off];
        tmp[1 - buf][t] = x;
        buf ^= 1;
        __syncthreads();
    }
    int incl = tmp[buf][t];
    if (i < n) excl[i] = incl - v;
    if (t == 255) bsums[blockIdx.x] = incl;
}

__global__ void scan2(int* __restrict__ bsums, int nb) {
    __shared__ int tmp[2][256];
    int t = threadIdx.x;
    int v = (t < nb) ? bsums[t] : 0;
    tmp[0][t] = v;
    __syncthreads();
    int buf = 0;
    for (int off = 1; off < 256; off <<= 1) {
        int x = tmp[buf][t];
        if (t >= off) x += tmp[buf][t - off];
        tmp[1 - buf][t] = x;
        buf ^= 1;
        __syncthreads();
    }
    if (t < nb) bsums[t] = tmp[buf][t] - v;   // exclusive
}

__global__ void scan3(int* __restrict__ excl, const int* __restrict__ bsums,
                      int* __restrict__ cursor, int n) {
    int i = blockIdx.x * 256 + threadIdx.x;
    if (i < n) {
        int o = excl[i] + bsums[blockIdx.x];
        excl[i] = o;
        cursor[i] = o;
    }
}

__global__ void scatter_sort(const int* __restrict__ edge_row,
                             const int* __restrict__ edge_col,
                             const float* __restrict__ edge_val,
                             int* __restrict__ cursor,
                             int2* __restrict__ sorted, int E) {
    int e = blockIdx.x * blockDim.x + threadIdx.x;
    if (e >= E) return;
    int row = edge_row[e];
    int p = atomicAdd(&cursor[row], 1);
    sorted[p] = make_int2(edge_col[e], __float_as_int(edge_val[e]));
}

// ---------------------------------------------------------------------------
// gather SpMM: 128 threads per row (2 rows per 256-block), no atomics.
// support written to d_out (reused in-place by the linear kernel).
// ---------------------------------------------------------------------------
__global__ void __launch_bounds__(256) spmm_gather(
    const float* __restrict__ x, const int2* __restrict__ sorted,
    const int* __restrict__ offsets, float* __restrict__ support,
    int N, int E) {
    int t = threadIdx.x & 127;
    int row = blockIdx.x * 2 + (threadIdx.x >> 7);
    if (row >= N) return;
    int start = offsets[row];
    int end = (row + 1 < N) ? offsets[row + 1] : E;
    float acc = 0.f;
    for (int e = start; e < end; ++e) {
        int2 cv = sorted[e];
        acc = fmaf(__int_as_float(cv.y), x[(size_t)cv.x * D + t], acc);
    }
    support[(size_t)row * D + t] = acc;
}

// ---------------------------------------------------------------------------
// fused linear + LayerNorm + ReLU, in place on hbuf (= d_out).
// TM=8 rows per 128-thread block; WT loads from L2 amortized 8x.
// ---------------------------------------------------------------------------
__global__ void __launch_bounds__(128) linear_ln_relu(
    float* __restrict__ hbuf,
    const float* __restrict__ WT,
    const float* __restrict__ b,
    const float* __restrict__ gamma,
    const float* __restrict__ beta,
    int N) {
    __shared__ float s[TM][D];
    __shared__ float mu_s[TM], inv_s[TM];
    int t = threadIdx.x;
    int row0 = blockIdx.x * TM;

#pragma unroll
    for (int r = 0; r < TM; ++r) {
        int row = row0 + r;
        s[r][t] = (row < N) ? hbuf[(size_t)row * D + t] : 0.f;
    }
    __syncthreads();

    float acc[TM];
#pragma unroll
    for (int r = 0; r < TM; ++r) acc[r] = 0.f;

    for (int k = 0; k < D; ++k) {
        float wt = WT[k * D + t];          // coalesced, L2-hot
#pragma unroll
        for (int r = 0; r < TM; ++r) acc[r] = fmaf(s[r][k], wt, acc[r]);
    }
    float bt = b[t];
#pragma unroll
    for (int r = 0; r < TM; ++r) acc[r] += bt;

    __syncthreads();                        // done reading s as inputs
#pragma unroll
    for (int r = 0; r < TM; ++r) s[r][t] = acc[r];
    __syncthreads();

    // LN stats: 16 threads per row
    int rr = t >> 4, j = t & 15;
    float sum = 0.f, sq = 0.f;
#pragma unroll
    for (int i = 0; i < 8; ++i) {
        float v = s[rr][j + 16 * i];
        sum += v;
        sq = fmaf(v, v, sq);
    }
#pragma unroll
    for (int off = 8; off > 0; off >>= 1) {
        sum += __shfl_down(sum, off, 16);
        sq  += __shfl_down(sq, off, 16);
    }
    if (j == 0) {
        float mu = sum * (1.0f / D);
        float var = sq * (1.0f / D) - mu * mu;
        mu_s[rr] = mu;
        inv_s[rr] = rsqrtf(var + LN_EPS);
    }
    __syncthreads();

    float g = gamma[t], be = beta[t];
#pragma unroll
    for (int r = 0; r < TM; ++r) {
        int row = row0 + r;
        if (row < N) {
            float y = (acc[r] - mu_s[r]) * inv_s[r] * g + be;
            hbuf[(size_t)row * D + t] = fmaxf(y, 0.f);
        }
    }
}

// ---------------------------------------------------------------------------
// Launch
// ---------------------------------------------------------------------------
extern "C" void kernel_launch(void* const* d_in, const int* in_sizes, int n_in,
                              void* d_out, int out_size, void* d_ws, size_t ws_size,
                              hipStream_t stream) {
    const float* x        = (const float*)d_in[0];
    const float* edge_val = (const float*)d_in[1];
    const float* W        = (const float*)d_in[2];
    const float* b        = (const float*)d_in[3];
    const float* gamma    = (const float*)d_in[4];
    const float* beta     = (const float*)d_in[5];
    const int*   edge_row = (const int*)d_in[6];
    const int*   edge_col = (const int*)d_in[7];

    const int N = in_sizes[0] / D;
    const int E = in_sizes[1];

    // workspace layout (8B-aligned first)
    char* ws = (char*)d_ws;
    int2*  sorted  = (int2*)ws;                 ws += (size_t)E * sizeof(int2);
    float* WT      = (float*)ws;                ws += (size_t)D * D * sizeof(float);
    int*   counts  = (int*)ws;                  ws += (size_t)N * sizeof(int);
    int*   offsets = (int*)ws;                  ws += (size_t)N * sizeof(int);
    int*   cursor  = (int*)ws;                  ws += (size_t)N * sizeof(int);
    int*   bsums   = (int*)ws;                  ws += 256 * sizeof(int);

    float* support = (float*)d_out;             // reuse output buffer

    hipMemsetAsync(counts, 0, (size_t)N * sizeof(int), stream);

    transpose_w<<<(D * D + 255) / 256, 256, 0, stream>>>(W, WT);

    hist_kernel<<<(E + 255) / 256, 256, 0, stream>>>(edge_row, counts, E);

    int nb = (N + 255) / 256;                   // 196 <= 256
    scan1<<<nb, 256, 0, stream>>>(counts, offsets, bsums, N);
    scan2<<<1, 256, 0, stream>>>(bsums, nb);
    scan3<<<nb, 256, 0, stream>>>(offsets, bsums, cursor, N);

    scatter_sort<<<(E + 255) / 256, 256, 0, stream>>>(edge_row, edge_col,
                                                      edge_val, cursor, sorted, E);

    spmm_gather<<<(N + 1) / 2, 256, 0, stream>>>(x, sorted, offsets, support, N, E);

    linear_ln_relu<<<(N + TM - 1) / TM, 128, 0, stream>>>(support, WT, b,
                                                          gamma, beta, N);
}

// Round 3
// 245.991 us; speedup vs baseline: 6.2369x; 1.4535x over previous
//
#include <hip/hip_runtime.h>
#include <hip/hip_bf16.h>

#define D 128
#define LN_EPS 1e-5f
#define RPB 8        // rows per block in fused kernel

// ---------------------------------------------------------------------------
// setup: zero counts[N] and transpose W -> WT in one dispatch
// ---------------------------------------------------------------------------
__global__ void setup_kernel(const float* __restrict__ W, float* __restrict__ WT,
                             int* __restrict__ counts, int N) {
    int i = blockIdx.x * blockDim.x + threadIdx.x;
    if (i < N) counts[i] = 0;
    if (i < D * D) WT[(i & (D - 1)) * D + (i >> 7)] = W[i];
}

// ---------------------------------------------------------------------------
// histogram of edge rows (int4-vectorized reads)
// ---------------------------------------------------------------------------
__global__ void hist_kernel(const int* __restrict__ edge_row,
                            int* __restrict__ counts, int E) {
    int i = blockIdx.x * blockDim.x + threadIdx.x;
    int e = i * 4;
    if (e + 3 < E) {
        int4 r = *(const int4*)(edge_row + e);
        atomicAdd(&counts[r.x], 1);
        atomicAdd(&counts[r.y], 1);
        atomicAdd(&counts[r.z], 1);
        atomicAdd(&counts[r.w], 1);
    } else {
        for (; e < E; ++e) atomicAdd(&counts[edge_row[e]], 1);
    }
}

// ---------------------------------------------------------------------------
// scan1: per-256-block inclusive scan -> exclusive offsets + block sums
// ---------------------------------------------------------------------------
__global__ void scan1(const int* __restrict__ counts, int* __restrict__ excl,
                      int* __restrict__ bsums, int n) {
    __shared__ int tmp[2][256];
    int t = threadIdx.x;
    int i = blockIdx.x * 256 + t;
    int v = (i < n) ? counts[i] : 0;
    tmp[0][t] = v;
    __syncthreads();
    int buf = 0;
    for (int off = 1; off < 256; off <<= 1) {
        int x = tmp[buf][t];
        if (t >= off) x += tmp[buf][t - off];
        tmp[1 - buf][t] = x;
        buf ^= 1;
        __syncthreads();
    }
    int incl = tmp[buf][t];
    if (i < n) excl[i] = incl - v;
    if (t == 255) bsums[blockIdx.x] = incl;
}

// ---------------------------------------------------------------------------
// scan23: each block redundantly scans bsums (nb<=256) in LDS, applies its
// exclusive prefix, writes final offsets + cursor copy.  (merges old scan2+3)
// ---------------------------------------------------------------------------
__global__ void scan23(int* __restrict__ excl, const int* __restrict__ bsums,
                       int* __restrict__ cursor, int n, int nb) {
    __shared__ int tmp[2][256];
    __shared__ int prefix;
    int t = threadIdx.x;
    int v = (t < nb) ? bsums[t] : 0;
    tmp[0][t] = v;
    __syncthreads();
    int buf = 0;
    for (int off = 1; off < 256; off <<= 1) {
        int x = tmp[buf][t];
        if (t >= off) x += tmp[buf][t - off];
        tmp[1 - buf][t] = x;
        buf ^= 1;
        __syncthreads();
    }
    if (t == 0) prefix = (blockIdx.x == 0) ? 0 : tmp[buf][blockIdx.x - 1];
    __syncthreads();
    int i = blockIdx.x * 256 + t;
    if (i < n) {
        int o = excl[i] + prefix;
        excl[i] = o;
        cursor[i] = o;
    }
}

// ---------------------------------------------------------------------------
// scatter edges into row-sorted (col,val) pairs
// ---------------------------------------------------------------------------
__global__ void scatter_sort(const int* __restrict__ edge_row,
                             const int* __restrict__ edge_col,
                             const float* __restrict__ edge_val,
                             int* __restrict__ cursor,
                             int2* __restrict__ sorted, int E) {
    int e = blockIdx.x * blockDim.x + threadIdx.x;
    if (e >= E) return;
    int row = edge_row[e];
    int p = atomicAdd(&cursor[row], 1);
    sorted[p] = make_int2(edge_col[e], __float_as_int(edge_val[e]));
}

// ---------------------------------------------------------------------------
// fused: gather SpMM (32 thr/row, float4, unroll-4 for MLP) -> LDS ->
// linear (h = s @ W^T + b) -> LayerNorm -> ReLU -> d_out
// ---------------------------------------------------------------------------
__global__ void __launch_bounds__(256) fused_gather_linear(
    const float* __restrict__ x, const int2* __restrict__ sorted,
    const int* __restrict__ offsets,
    const float* __restrict__ WT, const float* __restrict__ b,
    const float* __restrict__ gamma, const float* __restrict__ beta,
    float* __restrict__ out, int N, int E) {
    __shared__ float s[RPB][D];
    __shared__ float mu_s[RPB], inv_s[RPB];
    int t = threadIdx.x;
    int row0 = blockIdx.x * RPB;

    // ---- gather phase: 32 threads per row, float4 per lane ----
    {
        int r = t >> 5;            // 0..7
        int q = t & 31;            // float4 chunk
        int row = row0 + r;
        float4 acc = make_float4(0.f, 0.f, 0.f, 0.f);
        if (row < N) {
            int start = offsets[row];
            int end = (row + 1 < N) ? offsets[row + 1] : E;
            int e = start;
            for (; e + 4 <= end; e += 4) {
                int2 c0 = sorted[e], c1 = sorted[e + 1];
                int2 c2 = sorted[e + 2], c3 = sorted[e + 3];
                float4 v0 = *(const float4*)(x + (size_t)c0.x * D + q * 4);
                float4 v1 = *(const float4*)(x + (size_t)c1.x * D + q * 4);
                float4 v2 = *(const float4*)(x + (size_t)c2.x * D + q * 4);
                float4 v3 = *(const float4*)(x + (size_t)c3.x * D + q * 4);
                float w0 = __int_as_float(c0.y), w1 = __int_as_float(c1.y);
                float w2 = __int_as_float(c2.y), w3 = __int_as_float(c3.y);
                acc.x = fmaf(w0, v0.x, acc.x); acc.y = fmaf(w0, v0.y, acc.y);
                acc.z = fmaf(w0, v0.z, acc.z); acc.w = fmaf(w0, v0.w, acc.w);
                acc.x = fmaf(w1, v1.x, acc.x); acc.y = fmaf(w1, v1.y, acc.y);
                acc.z = fmaf(w1, v1.z, acc.z); acc.w = fmaf(w1, v1.w, acc.w);
                acc.x = fmaf(w2, v2.x, acc.x); acc.y = fmaf(w2, v2.y, acc.y);
                acc.z = fmaf(w2, v2.z, acc.z); acc.w = fmaf(w2, v2.w, acc.w);
                acc.x = fmaf(w3, v3.x, acc.x); acc.y = fmaf(w3, v3.y, acc.y);
                acc.z = fmaf(w3, v3.z, acc.z); acc.w = fmaf(w3, v3.w, acc.w);
            }
            for (; e < end; ++e) {
                int2 c = sorted[e];
                float4 v = *(const float4*)(x + (size_t)c.x * D + q * 4);
                float w = __int_as_float(c.y);
                acc.x = fmaf(w, v.x, acc.x); acc.y = fmaf(w, v.y, acc.y);
                acc.z = fmaf(w, v.z, acc.z); acc.w = fmaf(w, v.w, acc.w);
            }
        }
        *(float4*)&s[r][q * 4] = acc;
    }
    __syncthreads();

    // ---- linear phase: threads 0-127 -> rows 0-3, 128-255 -> rows 4-7 ----
    int td = t & 127;
    int rbase = (t >> 7) * 4;
    float acc[4] = {0.f, 0.f, 0.f, 0.f};
    for (int k = 0; k < D; ++k) {
        float wt = WT[k * D + td];
#pragma unroll
        for (int r = 0; r < 4; ++r) acc[r] = fmaf(s[rbase + r][k], wt, acc[r]);
    }
    float bt = b[td];
#pragma unroll
    for (int r = 0; r < 4; ++r) acc[r] += bt;

    __syncthreads();               // done reading s as linear inputs
#pragma unroll
    for (int r = 0; r < 4; ++r) s[rbase + r][td] = acc[r];
    __syncthreads();

    // ---- LN stats: 32 threads per row ----
    {
        int rr = t >> 5, j = t & 31;
        float sum = 0.f, sq = 0.f;
#pragma unroll
        for (int i = 0; i < 4; ++i) {
            float v = s[rr][j + 32 * i];
            sum += v;
            sq = fmaf(v, v, sq);
        }
#pragma unroll
        for (int off = 16; off > 0; off >>= 1) {
            sum += __shfl_down(sum, off, 32);
            sq  += __shfl_down(sq, off, 32);
        }
        if (j == 0) {
            float mu = sum * (1.0f / D);
            float var = sq * (1.0f / D) - mu * mu;
            mu_s[rr] = mu;
            inv_s[rr] = rsqrtf(var + LN_EPS);
        }
    }
    __syncthreads();

    // ---- normalize + ReLU + store ----
    float g = gamma[td], be = beta[td];
#pragma unroll
    for (int r = 0; r < 4; ++r) {
        int row = row0 + rbase + r;
        if (row < N) {
            float y = (acc[r] - mu_s[rbase + r]) * inv_s[rbase + r] * g + be;
            out[(size_t)row * D + td] = fmaxf(y, 0.f);
        }
    }
}

// ---------------------------------------------------------------------------
// Launch
// ---------------------------------------------------------------------------
extern "C" void kernel_launch(void* const* d_in, const int* in_sizes, int n_in,
                              void* d_out, int out_size, void* d_ws, size_t ws_size,
                              hipStream_t stream) {
    const float* x        = (const float*)d_in[0];
    const float* edge_val = (const float*)d_in[1];
    const float* W        = (const float*)d_in[2];
    const float* b        = (const float*)d_in[3];
    const float* gamma    = (const float*)d_in[4];
    const float* beta     = (const float*)d_in[5];
    const int*   edge_row = (const int*)d_in[6];
    const int*   edge_col = (const int*)d_in[7];

    const int N = in_sizes[0] / D;
    const int E = in_sizes[1];

    char* ws = (char*)d_ws;
    int2*  sorted  = (int2*)ws;                 ws += (size_t)E * sizeof(int2);
    float* WT      = (float*)ws;                ws += (size_t)D * D * sizeof(float);
    int*   counts  = (int*)ws;                  ws += (size_t)N * sizeof(int);
    int*   offsets = (int*)ws;                  ws += (size_t)N * sizeof(int);
    int*   cursor  = (int*)ws;                  ws += (size_t)N * sizeof(int);
    int*   bsums   = (int*)ws;                  ws += 256 * sizeof(int);

    int nb = (N + 255) / 256;   // 196 <= 256

    setup_kernel<<<(N + 255) / 256, 256, 0, stream>>>(W, WT, counts, N);
    hist_kernel<<<((E + 3) / 4 + 255) / 256, 256, 0, stream>>>(edge_row, counts, E);
    scan1<<<nb, 256, 0, stream>>>(counts, offsets, bsums, N);
    scan23<<<nb, 256, 0, stream>>>(offsets, bsums, cursor, N, nb);
    scatter_sort<<<(E + 255) / 256, 256, 0, stream>>>(edge_row, edge_col,
                                                      edge_val, cursor, sorted, E);
    fused_gather_linear<<<(N + RPB - 1) / RPB, 256, 0, stream>>>(
        x, sorted, offsets, WT, b, gamma, beta, (float*)d_out, N, E);
}